// Round 1
// baseline (158.397 us; speedup 1.0000x reference)
//
#include <hip/hip_runtime.h>
#include <hip/hip_bf16.h>
#include <math.h>

#define N_NODES 50000
#define N_EDGES 1600000
#define D_IN 128
#define D_OUT 32
#define ALPHA 0.2f

#define NB   1021    // one bucket per RPB rows (1021*49 = 50029 >= 50000)
#define NBP  1024    // padded bucket count for gcount/hist arrays
#define RPB  49      // rows per bucket
#define CAP  2048    // record slots per bucket (mean ~1567, +12 sigma)
#define PT   8       // edges per thread in edge kernel
#define PBK  256     // edge kernel block size
#define EB   (PT * PBK)                     // 2048 edges per edge-block
#define NPB  ((N_EDGES + EB - 1) / EB)      // 782 edge blocks
#define XNPB 32      // nodes per GEMM block
#define NXB  ((N_NODES + XNPB - 1) / XNPB)  // 1563 GEMM blocks
#define XLS  33      // padded X-tile stride in float4 (bank-conflict fix)

// Monotone float<->int key (involution). Works with signed atomicMin/Max.
__device__ __forceinline__ int enc_f(float x) {
    int i = __float_as_int(x);
    return i >= 0 ? i : (i ^ 0x7fffffff);
}
__device__ __forceinline__ float dec_f(int k) {
    return __int_as_float(k >= 0 ? k : (k ^ 0x7fffffff));
}
__device__ __forceinline__ unsigned short f2bf(float x) {
    __hip_bfloat16 h = __float2bfloat16(x);
    return *(unsigned short*)&h;
}
__device__ __forceinline__ float bf2f(unsigned short u) {
    return __uint_as_float((unsigned)u << 16);
}

// K1: GEMM X@W -> Xpb (bf16) AND s0/s1 epilogue.
// s0 = (X@W).a0 == X@(W@a0) — computed from the f32 Xp row already in
// registers (8 lanes x 4 dims per node): 8 FLOP + 3 shfl_xor per score.
// This deletes the old k_s kernel and its duplicate 25.6 MB X read.
// X tile padded to stride 33 float4: bank = (4g+4kk)%32 -> conflict-free
// (the old stride-32 layout was an 8-way conflict, 2.65M SQ_LDS_BANK_CONFLICT).
// Block 0 also inits gcount + minmax (absorbs the memset dispatch).
__global__ __launch_bounds__(256) void k_gemm(const float* __restrict__ X,
                                              const float* __restrict__ W,
                                              const float* __restrict__ a0,
                                              const float* __restrict__ a1,
                                              unsigned short* __restrict__ Xpb,
                                              float* __restrict__ s0,
                                              float* __restrict__ s1,
                                              int* __restrict__ minmax,
                                              int* __restrict__ gcount) {
    __shared__ float4 Wl4[1024];        // 16 KB
    __shared__ float4 Xl4[XNPB * XLS];  // 16.9 KB (padded)
    const int tid = threadIdx.x;
    if (blockIdx.x == 0) {
        if (tid == 0) {
            minmax[0] = 0x7fffffff;      // running min key
            minmax[1] = (int)0x80000000; // running max key
        }
        for (int i = tid; i < NBP; i += 256) gcount[i] = 0;
    }
    const int node0 = blockIdx.x * XNPB;
    {
        const float4* W4 = (const float4*)W;
#pragma unroll
        for (int i = 0; i < 4; ++i) Wl4[tid + 256 * i] = W4[tid + 256 * i];
        const float4* X4 = (const float4*)X + (size_t)node0 * (D_IN / 4);
        const int lim = (min(XNPB, N_NODES - node0)) * (D_IN / 4);
#pragma unroll
        for (int i = 0; i < 4; ++i) {
            const int idx = tid + 256 * i;
            const float4 v = (idx < lim) ? X4[idx]
                                         : make_float4(0.f, 0.f, 0.f, 0.f);
            Xl4[(idx >> 5) * XLS + (idx & 31)] = v;
        }
    }
    __syncthreads();
    const int g = tid >> 3;  // node within block (0..31)
    const int l = tid & 7;   // lane -> dims [4l, 4l+4)
    const int node = node0 + g;
    const float4* xr = &Xl4[g * XLS];
    float ax = 0.f, ay = 0.f, az = 0.f, aw = 0.f;
#pragma unroll 4
    for (int kk = 0; kk < D_IN / 4; ++kk) {
        const float4 xv = xr[kk];
        const float4 w0 = Wl4[(4 * kk + 0) * 8 + l];
        const float4 w1 = Wl4[(4 * kk + 1) * 8 + l];
        const float4 w2 = Wl4[(4 * kk + 2) * 8 + l];
        const float4 w3 = Wl4[(4 * kk + 3) * 8 + l];
        ax += xv.x * w0.x + xv.y * w1.x + xv.z * w2.x + xv.w * w3.x;
        ay += xv.x * w0.y + xv.y * w1.y + xv.z * w2.y + xv.w * w3.y;
        az += xv.x * w0.z + xv.y * w1.z + xv.z * w2.z + xv.w * w3.z;
        aw += xv.x * w0.w + xv.y * w1.w + xv.z * w2.w + xv.w * w3.w;
    }
    if (node < N_NODES) {
        uint2 pk;
        pk.x = ((unsigned)f2bf(ay) << 16) | f2bf(ax);
        pk.y = ((unsigned)f2bf(aw) << 16) | f2bf(az);
        ((uint2*)Xpb)[(size_t)node * 8 + l] = pk;
        // score epilogue: dot f32 Xp row with a0/a1, reduce over 8 lanes
        const float4 av0 = ((const float4*)a0)[l];
        const float4 av1 = ((const float4*)a1)[l];
        float v0 = ax * av0.x + ay * av0.y + az * av0.z + aw * av0.w;
        float v1 = ax * av1.x + ay * av1.y + az * av1.z + aw * av1.w;
#pragma unroll
        for (int m = 4; m >= 1; m >>= 1) {
            v0 += __shfl_xor(v0, m);
            v1 += __shfl_xor(v1, m);
        }
        if (l == 0) { s0[node] = v0; s1[node] = v1; }
    }
}

// K2: edge pass only (own kernel -> 782 blocks, ~12 waves/CU for the
// latency-bound random s0/s1 gathers, vs 1.5 blocks/CU before).
// score = leaky(s0[r]+s1[c]); global minmax; bucketize DIRECTLY at 49-row
// granularity into 8B records {lr:6|col:16, score} so K3 blocks scan only
// their own records (halves K3 scan work).
__global__ __launch_bounds__(256) void k_edge(const int* __restrict__ row,
                                              const int* __restrict__ col,
                                              const float* __restrict__ s0,
                                              const float* __restrict__ s1,
                                              int* __restrict__ minmax,
                                              int* __restrict__ gcount,
                                              uint2* __restrict__ gEdges) {
    __shared__ int hist[NBP];  // 4 KB
    __shared__ int lcur[NBP];  // 4 KB
    __shared__ int smn[4], smx[4];
    const int tid = threadIdx.x;
    for (int i = tid; i < NBP; i += PBK) hist[i] = 0;
    __syncthreads();
    const int base = blockIdx.x * EB;
    unsigned px[PT]; // (b:10 | lr:6 | col:16)
    float    fa[PT]; // leaky-relu'd score
    int cnt = 0;
    int kmin = 0x7fffffff, kmax = 0x80000000;
    if (base + EB <= N_EDGES) { // full block: int4 vector loads
#pragma unroll
        for (int i = 0; i < PT / 4; ++i) {
            const int4 r4 = ((const int4*)(row + base))[tid + i * PBK];
            const int4 c4 = ((const int4*)(col + base))[tid + i * PBK];
            const int rr[4] = {r4.x, r4.y, r4.z, r4.w};
            const int cc[4] = {c4.x, c4.y, c4.z, c4.w};
#pragma unroll
            for (int j = 0; j < 4; ++j) {
                const int r = rr[j];
                const int c = cc[j];
                float a = s0[r] + s1[c];
                a = a > 0.f ? a : ALPHA * a;
                const int k = enc_f(a);
                kmin = min(kmin, k);
                kmax = max(kmax, k);
                const unsigned b = (unsigned)r / RPB;
                const unsigned lr = (unsigned)r - b * RPB;
                px[cnt] = (b << 22) | (lr << 16) | (unsigned)c;
                fa[cnt] = a;
                ++cnt;
                atomicAdd(&hist[b], 1);
            }
        }
    } else {                    // tail block: scalar guarded
#pragma unroll
        for (int i = 0; i < PT; ++i) {
            const int e = base + i * PBK + tid;
            if (e >= N_EDGES) break;
            const int r = row[e];
            const int c = col[e];
            float a = s0[r] + s1[c];
            a = a > 0.f ? a : ALPHA * a;
            const int k = enc_f(a);
            kmin = min(kmin, k);
            kmax = max(kmax, k);
            const unsigned b = (unsigned)r / RPB;
            const unsigned lr = (unsigned)r - b * RPB;
            px[cnt] = (b << 22) | (lr << 16) | (unsigned)c;
            fa[cnt] = a;
            ++cnt;
            atomicAdd(&hist[b], 1);
        }
    }
    __syncthreads();
    for (int i = tid; i < NBP; i += PBK) {
        const int h = hist[i];
        lcur[i] = h > 0 ? atomicAdd(&gcount[i], h) : 0;
    }
    __syncthreads();
    for (int j = 0; j < cnt; ++j) {
        const unsigned p = px[j];
        const unsigned b = p >> 22;
        const int pos = atomicAdd(&lcur[b], 1);
        if (pos < CAP)
            gEdges[(size_t)b * CAP + pos] =
                make_uint2(p & 0x3FFFFFu, (unsigned)__float_as_int(fa[j]));
    }
#pragma unroll
    for (int m = 32; m >= 1; m >>= 1) {
        kmin = min(kmin, __shfl_xor(kmin, m));
        kmax = max(kmax, __shfl_xor(kmax, m));
    }
    const int wave = tid >> 6;
    if ((tid & 63) == 0) { smn[wave] = kmin; smx[wave] = kmax; }
    __syncthreads();
    if (tid == 0) {
#pragma unroll
        for (int w = 1; w < 4; ++w) {
            kmin = min(kmin, smn[w]);
            kmax = max(kmax, smx[w]);
        }
        atomicMin(&minmax[0], kmin);
        atomicMax(&minmax[1], kmax);
    }
}

// K3: one 512-thread block per 49-row bucket (1021 blocks, ~12.3 KB LDS).
// pass 1: LDS histogram of this bucket's rows (49 bins);
// pass 2: counting-sort scatter {col:u16, exp(minmaxnorm(score))};
// rows:   32 row-processors x 16 lanes (2 bf16 dims per lane via one u32
//         load — half the VMEM instructions of the u16 layout at the same
//         64 B/edge traffic), 4-way unrolled register accumulators,
//         out written as float2.
__global__ __launch_bounds__(512, 8) void k_bucket(const int* __restrict__ gcount,
                                                   const uint2* __restrict__ gEdges,
                                                   const unsigned short* __restrict__ Xpb,
                                                   const int* __restrict__ minmax,
                                                   float* __restrict__ out) {
    __shared__ unsigned short scol[CAP]; // 4 KB
    __shared__ float swt[CAP];           // 8 KB
    __shared__ int off[RPB + 1];
    __shared__ int cur[RPB];
    const int b = blockIdx.x;
    const int t = threadIdx.x;
    const float mn = dec_f(minmax[0]);
    const float mx = dec_f(minmax[1]);
    const float inv = 1.0f / (mx - mn);
    const int cnt = min(gcount[b], CAP);
    const uint2* eb = gEdges + (size_t)b * CAP;

    if (t < RPB) cur[t] = 0;  // temp hist
    __syncthreads();
    for (int i = t; i < cnt; i += 512) atomicAdd(&cur[eb[i].x >> 16], 1);
    __syncthreads();
    if (t == 0) {
        int run = 0;
#pragma unroll
        for (int r = 0; r < RPB; ++r) { off[r] = run; run += cur[r]; }
        off[RPB] = run;
    }
    __syncthreads();
    if (t < RPB) cur[t] = off[t];
    __syncthreads();
    // pass 2: counting-sort scatter (exp computed once per edge)
    for (int i = t; i < cnt; i += 512) {
        const uint2 e = eb[i];
        const int lr = (int)(e.x >> 16);
        const int p = atomicAdd(&cur[lr], 1);
        if (p < CAP) {
            scol[p] = (unsigned short)(e.x & 0xFFFFu);
            swt[p] = __expf((__int_as_float(e.y) - mn) * inv);
        }
    }
    __syncthreads();

    // row processing: 32 processors x 16 lanes, 2 dims/lane, 4-way unroll
    const int proc = t >> 4;  // 0..31
    const int d2 = t & 15;    // dims [2*d2, 2*d2+1]
    const unsigned* Xp32 = (const unsigned*)Xpb;
    for (int lr = proc; lr < RPB; lr += 32) {
        const int s = off[lr];
        const int e2 = off[lr + 1];
        float pa0 = 0.f, pa1 = 0.f, pa2 = 0.f, pa3 = 0.f;
        float pb0 = 0.f, pb1 = 0.f, pb2 = 0.f, pb3 = 0.f;
        float w0s = 0.f, w1s = 0.f, w2s = 0.f, w3s = 0.f;
        int i = s;
        for (; i + 3 < e2; i += 4) {
            const int c0 = scol[i];
            const int c1 = scol[i + 1];
            const int c2 = scol[i + 2];
            const int c3 = scol[i + 3];
            const float w0 = swt[i];
            const float w1 = swt[i + 1];
            const float w2 = swt[i + 2];
            const float w3 = swt[i + 3];
            const unsigned u0 = Xp32[(size_t)c0 * 16 + d2];
            const unsigned u1 = Xp32[(size_t)c1 * 16 + d2];
            const unsigned u2 = Xp32[(size_t)c2 * 16 + d2];
            const unsigned u3 = Xp32[(size_t)c3 * 16 + d2];
            pa0 += w0 * bf2f((unsigned short)(u0 & 0xFFFFu));
            pb0 += w0 * bf2f((unsigned short)(u0 >> 16));
            pa1 += w1 * bf2f((unsigned short)(u1 & 0xFFFFu));
            pb1 += w1 * bf2f((unsigned short)(u1 >> 16));
            pa2 += w2 * bf2f((unsigned short)(u2 & 0xFFFFu));
            pb2 += w2 * bf2f((unsigned short)(u2 >> 16));
            pa3 += w3 * bf2f((unsigned short)(u3 & 0xFFFFu));
            pb3 += w3 * bf2f((unsigned short)(u3 >> 16));
            w0s += w0; w1s += w1; w2s += w2; w3s += w3;
        }
        for (; i < e2; ++i) {
            const float w = swt[i];
            const unsigned u = Xp32[(size_t)scol[i] * 16 + d2];
            pa0 += w * bf2f((unsigned short)(u & 0xFFFFu));
            pb0 += w * bf2f((unsigned short)(u >> 16));
            w0s += w;
        }
        const int r = b * RPB + lr;
        if (r < N_NODES) {
            const float ws = w0s + w1s + w2s + w3s;
            float2 o;
            o.x = (pa0 + pa1 + pa2 + pa3) / ws;
            o.y = (pb0 + pb1 + pb2 + pb3) / ws;
            ((float2*)out)[(size_t)r * 16 + d2] = o;
        }
    }
}

extern "C" void kernel_launch(void* const* d_in, const int* in_sizes, int n_in,
                              void* d_out, int out_size, void* d_ws, size_t ws_size,
                              hipStream_t stream) {
    const float* X  = (const float*)d_in[0];
    const float* W  = (const float*)d_in[1];
    const float* a0 = (const float*)d_in[2];
    const float* a1 = (const float*)d_in[3];
    const int* row  = (const int*)d_in[4];
    const int* col  = (const int*)d_in[5];
    float* out = (float*)d_out;

    // Workspace layout (4B units):
    // [minmax: 64][gcount: 2048][s0: 50048][s1: 50048]
    // [Xpb: 1.6M u16 = 800000 u32][gEdges: NB*CAP uint2]
    float* ws = (float*)d_ws;
    int*   minmax = (int*)ws;
    int*   gcount = (int*)(ws + 64);
    float* s0 = ws + 64 + 2048;
    float* s1 = s0 + 50048;
    unsigned short* Xpb = (unsigned short*)(s1 + 50048); // 16B-aligned
    uint2* gEdges = (uint2*)(s1 + 50048 + 800000);       // after 1.6M u16

    k_gemm<<<NXB, 256, 0, stream>>>(X, W, a0, a1, Xpb, s0, s1, minmax, gcount);
    k_edge<<<NPB, 256, 0, stream>>>(row, col, s0, s1, minmax, gcount, gEdges);
    k_bucket<<<NB, 512, 0, stream>>>(gcount, gEdges, Xpb, minmax, out);
}

// Round 3
// 156.629 us; speedup vs baseline: 1.0113x; 1.0113x over previous
//
#include <hip/hip_runtime.h>
#include <hip/hip_bf16.h>
#include <math.h>

#define N_NODES 50000
#define N_EDGES 1600000
#define D_IN 128
#define D_OUT 32
#define ALPHA 0.2f

#define NB   1021    // one bucket per RPB rows (1021*49 = 50029 >= 50000)
#define NBP  1024    // padded bucket count for gcount/hist arrays
#define RPB  49      // rows per bucket
#define CAP  2048    // record slots per bucket (mean ~1567, +12 sigma)
#define GST  16      // gcount stride in ints: ONE counter per 64B line
                     // (unpadded 64-line array serialized ~10.7K RMW/line
                     //  at L2 -> the whole 46us of k_edge; see R2 theory)
#define PT   8       // edges per thread in edge path
#define PBK  256     // block size
#define EB   (PT * PBK)                     // 2048 edges per edge-block
#define NPB  ((N_EDGES + EB - 1) / EB)      // 782 edge blocks
#define XNPB 32      // nodes per GEMM block
#define NXB  ((N_NODES + XNPB - 1) / XNPB)  // 1563 GEMM blocks
#define XLS  33      // padded X-tile stride in float4 (bank-conflict fix)
#define SNPB 32      // nodes per k_s block

// Monotone float<->int key (involution). Works with signed atomicMin/Max.
__device__ __forceinline__ int enc_f(float x) {
    int i = __float_as_int(x);
    return i >= 0 ? i : (i ^ 0x7fffffff);
}
__device__ __forceinline__ float dec_f(int k) {
    return __int_as_float(k >= 0 ? k : (k ^ 0x7fffffff));
}
__device__ __forceinline__ unsigned short f2bf(float x) {
    __hip_bfloat16 h = __float2bfloat16(x);
    return *(unsigned short*)&h;
}
__device__ __forceinline__ float bf2f(unsigned short u) {
    return __uint_as_float((unsigned)u << 16);
}

// K1: s0 = X @ (W@a0), s1 = X @ (W@a1) — GEMV so the edge blocks of the
// fused K2 have scores available (enables GEMM/edge overlap there).
// 32 nodes per 256-thread block, 8 lanes per node (coalesced 512B/row).
// Block 0 also inits PADDED gcount + minmax (absorbs memset dispatches).
__global__ __launch_bounds__(256) void k_s(const float* __restrict__ X,
                                           const float* __restrict__ W,
                                           const float* __restrict__ a0,
                                           const float* __restrict__ a1,
                                           float* __restrict__ s0,
                                           float* __restrict__ s1,
                                           int* __restrict__ minmax,
                                           int* __restrict__ gcount) {
    __shared__ float wa0[D_IN], wa1[D_IN];
    const int tid = threadIdx.x;
    if (blockIdx.x == 0) {
        if (tid == 0) {
            minmax[0] = 0x7fffffff;      // running min key
            minmax[1] = (int)0x80000000; // running max key
        }
        int4* g4 = (int4*)gcount;
        for (int i = tid; i < NBP * GST / 4; i += 256)
            g4[i] = make_int4(0, 0, 0, 0);
    }
    {   // wa0/wa1: W row k dotted with a0/a1 (redundant per block, L2-hot)
        const int k = tid & 127;
        const float4* Wr = (const float4*)(W + k * D_OUT);
        const float4* A = (const float4*)((tid < 128) ? a0 : a1);
        float acc = 0.f;
#pragma unroll
        for (int j = 0; j < 8; ++j) {
            const float4 w = Wr[j];
            const float4 a = A[j];
            acc += w.x * a.x + w.y * a.y + w.z * a.z + w.w * a.w;
        }
        if (tid < 128) wa0[k] = acc; else wa1[k] = acc;
    }
    __syncthreads();
    const int node = blockIdx.x * SNPB + (tid >> 3);
    const int l = tid & 7;  // lane -> k-range [16l, 16l+16)
    if (node < N_NODES) {
        const float4* xr = (const float4*)(X + (size_t)node * D_IN) + l * 4;
        const float4* p4 = (const float4*)wa0 + l * 4;
        const float4* q4 = (const float4*)wa1 + l * 4;
        float v0 = 0.f, v1 = 0.f;
#pragma unroll
        for (int j = 0; j < 4; ++j) {
            const float4 x = xr[j];
            const float4 p = p4[j];
            const float4 q = q4[j];
            v0 += x.x * p.x + x.y * p.y + x.z * p.z + x.w * p.w;
            v1 += x.x * q.x + x.y * q.y + x.z * q.z + x.w * q.w;
        }
#pragma unroll
        for (int m = 4; m >= 1; m >>= 1) {
            v0 += __shfl_xor(v0, m);
            v1 += __shfl_xor(v1, m);
        }
        if (l == 0) { s0[node] = v0; s1[node] = v1; }
    }
}

// K2: heterogeneous fused dispatch, INTERLEAVED 1 edge : 2 GEMM blocks
// (bid%3==0 -> edge) so latency-bound edge blocks co-reside with
// VALU-dense GEMM blocks from the start.
// GEMM path: X@W -> Xpb (bf16), padded-stride LDS X tile (conflict-free).
// Edge path: score = leaky(s0[r]+s1[c]) (s0/s1 from K1, L2-resident),
//            global minmax, bucketize into 8B records {lr:6|col:16, score}.
//            gcount atomics hit padded one-counter-per-line slots.
__global__ __launch_bounds__(256) void k_fused(const float* __restrict__ X,
                                               const float* __restrict__ W,
                                               const int* __restrict__ row,
                                               const int* __restrict__ col,
                                               const float* __restrict__ s0,
                                               const float* __restrict__ s1,
                                               unsigned short* __restrict__ Xpb,
                                               int* __restrict__ minmax,
                                               int* __restrict__ gcount,
                                               uint2* __restrict__ gEdges) {
    __shared__ char smem[33280] __attribute__((aligned(16)));
    const int tid = threadIdx.x;
    const int bid = blockIdx.x;
    if (bid % 3 != 0) {
        // ---------------- GEMM path ----------------
        const int gid = bid - bid / 3 - 1;   // 0..1563
        if (gid >= NXB) return;
        float4* Wl4 = (float4*)smem;             // 16 KB
        float4* Xl4 = (float4*)(smem + 16384);   // 16.9 KB (padded stride 33)
        const int node0 = gid * XNPB;
        {
            const float4* W4 = (const float4*)W;
#pragma unroll
            for (int i = 0; i < 4; ++i) Wl4[tid + 256 * i] = W4[tid + 256 * i];
            const float4* X4 = (const float4*)X + (size_t)node0 * (D_IN / 4);
            const int lim = (min(XNPB, N_NODES - node0)) * (D_IN / 4);
#pragma unroll
            for (int i = 0; i < 4; ++i) {
                const int idx = tid + 256 * i;
                const float4 v = (idx < lim) ? X4[idx]
                                             : make_float4(0.f, 0.f, 0.f, 0.f);
                Xl4[(idx >> 5) * XLS + (idx & 31)] = v;
            }
        }
        __syncthreads();
        const int g = tid >> 3;  // node within block (0..31)
        const int l = tid & 7;   // lane -> dims [4l, 4l+4)
        const int node = node0 + g;
        const float4* xr = &Xl4[g * XLS];
        float ax = 0.f, ay = 0.f, az = 0.f, aw = 0.f;
#pragma unroll 4
        for (int kk = 0; kk < D_IN / 4; ++kk) {
            const float4 xv = xr[kk];
            const float4 w0 = Wl4[(4 * kk + 0) * 8 + l];
            const float4 w1 = Wl4[(4 * kk + 1) * 8 + l];
            const float4 w2 = Wl4[(4 * kk + 2) * 8 + l];
            const float4 w3 = Wl4[(4 * kk + 3) * 8 + l];
            ax += xv.x * w0.x + xv.y * w1.x + xv.z * w2.x + xv.w * w3.x;
            ay += xv.x * w0.y + xv.y * w1.y + xv.z * w2.y + xv.w * w3.y;
            az += xv.x * w0.z + xv.y * w1.z + xv.z * w2.z + xv.w * w3.z;
            aw += xv.x * w0.w + xv.y * w1.w + xv.z * w2.w + xv.w * w3.w;
        }
        if (node < N_NODES) {
            uint2 pk;
            pk.x = ((unsigned)f2bf(ay) << 16) | f2bf(ax);
            pk.y = ((unsigned)f2bf(aw) << 16) | f2bf(az);
            ((uint2*)Xpb)[(size_t)node * 8 + l] = pk;
        }
    } else {
        // ---------------- edge path: score + minmax + bucketize ----------
        const int bb = bid / 3;              // 0..781
        if (bb >= NPB) return;
        int* hist = (int*)smem;            // NBP ints = 4 KB
        int* lcur = (int*)(smem + 4096);   // NBP ints = 4 KB
        int* smn  = (int*)(smem + 8192);   // 4 ints
        int* smx  = (int*)(smem + 8256);   // 4 ints
        for (int i = tid; i < NBP; i += PBK) hist[i] = 0;
        __syncthreads();
        const int base = bb * EB;
        unsigned px[PT]; // (b:10 | lr:6 | col:16)
        float    fa[PT]; // leaky-relu'd score
        int cnt = 0;
        int kmin = 0x7fffffff, kmax = 0x80000000;
        if (base + EB <= N_EDGES) { // full block: int4 vector loads
#pragma unroll
            for (int i = 0; i < PT / 4; ++i) {
                const int4 r4 = ((const int4*)(row + base))[tid + i * PBK];
                const int4 c4 = ((const int4*)(col + base))[tid + i * PBK];
                const int rr[4] = {r4.x, r4.y, r4.z, r4.w};
                const int cc[4] = {c4.x, c4.y, c4.z, c4.w};
#pragma unroll
                for (int j = 0; j < 4; ++j) {
                    const int r = rr[j];
                    const int c = cc[j];
                    float a = s0[r] + s1[c];
                    a = a > 0.f ? a : ALPHA * a;
                    const int k = enc_f(a);
                    kmin = min(kmin, k);
                    kmax = max(kmax, k);
                    const unsigned b = (unsigned)r / RPB;
                    const unsigned lr = (unsigned)r - b * RPB;
                    px[cnt] = (b << 22) | (lr << 16) | (unsigned)c;
                    fa[cnt] = a;
                    ++cnt;
                    atomicAdd(&hist[b], 1);
                }
            }
        } else {                    // tail block: scalar guarded
#pragma unroll
            for (int i = 0; i < PT; ++i) {
                const int e = base + i * PBK + tid;
                if (e >= N_EDGES) break;
                const int r = row[e];
                const int c = col[e];
                float a = s0[r] + s1[c];
                a = a > 0.f ? a : ALPHA * a;
                const int k = enc_f(a);
                kmin = min(kmin, k);
                kmax = max(kmax, k);
                const unsigned b = (unsigned)r / RPB;
                const unsigned lr = (unsigned)r - b * RPB;
                px[cnt] = (b << 22) | (lr << 16) | (unsigned)c;
                fa[cnt] = a;
                ++cnt;
                atomicAdd(&hist[b], 1);
            }
        }
        __syncthreads();
        for (int i = tid; i < NBP; i += PBK) {
            const int h = hist[i];
            lcur[i] = h > 0 ? atomicAdd(&gcount[i << 4], h) : 0;  // padded
        }
        __syncthreads();
        for (int j = 0; j < cnt; ++j) {
            const unsigned p = px[j];
            const unsigned b = p >> 22;
            const int pos = atomicAdd(&lcur[b], 1);
            if (pos < CAP)
                gEdges[(size_t)b * CAP + pos] =
                    make_uint2(p & 0x3FFFFFu, (unsigned)__float_as_int(fa[j]));
        }
#pragma unroll
        for (int m = 32; m >= 1; m >>= 1) {
            kmin = min(kmin, __shfl_xor(kmin, m));
            kmax = max(kmax, __shfl_xor(kmax, m));
        }
        const int wave = tid >> 6;
        if ((tid & 63) == 0) { smn[wave] = kmin; smx[wave] = kmax; }
        __syncthreads();
        if (tid == 0) {
#pragma unroll
            for (int w = 1; w < 4; ++w) {
                kmin = min(kmin, smn[w]);
                kmax = max(kmax, smx[w]);
            }
            atomicMin(&minmax[0], kmin);
            atomicMax(&minmax[1], kmax);
        }
    }
}

// K3: one 512-thread block per 49-row bucket (1021 blocks, ~12.3 KB LDS).
// pass 1: LDS histogram of this bucket's rows (49 bins);
// pass 2: counting-sort scatter {col:u16, exp(minmaxnorm(score))};
// rows:   32 row-processors x 16 lanes (2 bf16 dims per lane via one u32
//         load), 4-way unrolled register accumulators, float2 out.
__global__ __launch_bounds__(512, 8) void k_bucket(const int* __restrict__ gcount,
                                                   const uint2* __restrict__ gEdges,
                                                   const unsigned short* __restrict__ Xpb,
                                                   const int* __restrict__ minmax,
                                                   float* __restrict__ out) {
    __shared__ unsigned short scol[CAP]; // 4 KB
    __shared__ float swt[CAP];           // 8 KB
    __shared__ int off[RPB + 1];
    __shared__ int cur[RPB];
    const int b = blockIdx.x;
    const int t = threadIdx.x;
    const float mn = dec_f(minmax[0]);
    const float mx = dec_f(minmax[1]);
    const float inv = 1.0f / (mx - mn);
    const int cnt = min(gcount[b << 4], CAP);   // padded gcount
    const uint2* eb = gEdges + (size_t)b * CAP;

    if (t < RPB) cur[t] = 0;  // temp hist
    __syncthreads();
    for (int i = t; i < cnt; i += 512) atomicAdd(&cur[eb[i].x >> 16], 1);
    __syncthreads();
    if (t == 0) {
        int run = 0;
#pragma unroll
        for (int r = 0; r < RPB; ++r) { off[r] = run; run += cur[r]; }
        off[RPB] = run;
    }
    __syncthreads();
    if (t < RPB) cur[t] = off[t];
    __syncthreads();
    // pass 2: counting-sort scatter (exp computed once per edge)
    for (int i = t; i < cnt; i += 512) {
        const uint2 e = eb[i];
        const int lr = (int)(e.x >> 16);
        const int p = atomicAdd(&cur[lr], 1);
        if (p < CAP) {
            scol[p] = (unsigned short)(e.x & 0xFFFFu);
            swt[p] = __expf((__int_as_float(e.y) - mn) * inv);
        }
    }
    __syncthreads();

    // row processing: 32 processors x 16 lanes, 2 dims/lane, 4-way unroll
    const int proc = t >> 4;  // 0..31
    const int d2 = t & 15;    // dims [2*d2, 2*d2+1]
    const unsigned* Xp32 = (const unsigned*)Xpb;
    for (int lr = proc; lr < RPB; lr += 32) {
        const int s = off[lr];
        const int e2 = off[lr + 1];
        float pa0 = 0.f, pa1 = 0.f, pa2 = 0.f, pa3 = 0.f;
        float pb0 = 0.f, pb1 = 0.f, pb2 = 0.f, pb3 = 0.f;
        float w0s = 0.f, w1s = 0.f, w2s = 0.f, w3s = 0.f;
        int i = s;
        for (; i + 3 < e2; i += 4) {
            const int c0 = scol[i];
            const int c1 = scol[i + 1];
            const int c2 = scol[i + 2];
            const int c3 = scol[i + 3];
            const float w0 = swt[i];
            const float w1 = swt[i + 1];
            const float w2 = swt[i + 2];
            const float w3 = swt[i + 3];
            const unsigned u0 = Xp32[(size_t)c0 * 16 + d2];
            const unsigned u1 = Xp32[(size_t)c1 * 16 + d2];
            const unsigned u2 = Xp32[(size_t)c2 * 16 + d2];
            const unsigned u3 = Xp32[(size_t)c3 * 16 + d2];
            pa0 += w0 * bf2f((unsigned short)(u0 & 0xFFFFu));
            pb0 += w0 * bf2f((unsigned short)(u0 >> 16));
            pa1 += w1 * bf2f((unsigned short)(u1 & 0xFFFFu));
            pb1 += w1 * bf2f((unsigned short)(u1 >> 16));
            pa2 += w2 * bf2f((unsigned short)(u2 & 0xFFFFu));
            pb2 += w2 * bf2f((unsigned short)(u2 >> 16));
            pa3 += w3 * bf2f((unsigned short)(u3 & 0xFFFFu));
            pb3 += w3 * bf2f((unsigned short)(u3 >> 16));
            w0s += w0; w1s += w1; w2s += w2; w3s += w3;
        }
        for (; i < e2; ++i) {
            const float w = swt[i];
            const unsigned u = Xp32[(size_t)scol[i] * 16 + d2];
            pa0 += w * bf2f((unsigned short)(u & 0xFFFFu));
            pb0 += w * bf2f((unsigned short)(u >> 16));
            w0s += w;
        }
        const int r = b * RPB + lr;
        if (r < N_NODES) {
            const float ws = w0s + w1s + w2s + w3s;
            float2 o;
            o.x = (pa0 + pa1 + pa2 + pa3) / ws;
            o.y = (pb0 + pb1 + pb2 + pb3) / ws;
            ((float2*)out)[(size_t)r * 16 + d2] = o;
        }
    }
}

extern "C" void kernel_launch(void* const* d_in, const int* in_sizes, int n_in,
                              void* d_out, int out_size, void* d_ws, size_t ws_size,
                              hipStream_t stream) {
    const float* X  = (const float*)d_in[0];
    const float* W  = (const float*)d_in[1];
    const float* a0 = (const float*)d_in[2];
    const float* a1 = (const float*)d_in[3];
    const int* row  = (const int*)d_in[4];
    const int* col  = (const int*)d_in[5];
    float* out = (float*)d_out;

    // Workspace layout (4B units):
    // [minmax: 64][gcount padded: NBP*GST = 16384][s0: 50048][s1: 50048]
    // [Xpb: 1.6M u16 = 800000 u32][gEdges: NB*CAP uint2]  (~20.4 MB)
    float* ws = (float*)d_ws;
    int*   minmax = (int*)ws;
    int*   gcount = (int*)(ws + 64);
    float* s0 = ws + 64 + NBP * GST;
    float* s1 = s0 + 50048;
    unsigned short* Xpb = (unsigned short*)(s1 + 50048); // 8B-aligned
    uint2* gEdges = (uint2*)(s1 + 50048 + 800000);       // after 1.6M u16

    k_s<<<(N_NODES + SNPB - 1) / SNPB, 256, 0, stream>>>(X, W, a0, a1, s0, s1,
                                                         minmax, gcount);
    k_fused<<<NXB + NPB + 1, 256, 0, stream>>>(X, W, row, col, s0, s1, Xpb,
                                               minmax, gcount, gEdges);
    k_bucket<<<NB, 512, 0, stream>>>(gcount, gEdges, Xpb, minmax, out);
}